// Round 5
// baseline (562.553 us; speedup 1.0000x reference)
//
#include <hip/hip_runtime.h>

#define M1 98304
#define RDIM 512
#define FDIM 2048
#define SDIM 96

typedef __attribute__((ext_vector_type(8))) __bf16 bf16x8;
typedef __attribute__((ext_vector_type(4))) float f32x4;

union U16x8 { uint4 u; unsigned short s[8]; };

#define WAITV6 asm volatile("s_waitcnt vmcnt(6)" ::: "memory")
#define WAITV5 asm volatile("s_waitcnt vmcnt(5)" ::: "memory")
#define WAITV0 asm volatile("s_waitcnt vmcnt(0)" ::: "memory")
#define WAITL0 asm volatile("s_waitcnt lgkmcnt(0)" ::: "memory")
#define SBAR   __builtin_amdgcn_s_barrier()
#define SCHED0 __builtin_amdgcn_sched_barrier(0)

__device__ __forceinline__ float bf2f(unsigned short u){
  union { unsigned int i; float f; } v; v.i = ((unsigned int)u) << 16; return v.f;
}
__device__ __forceinline__ unsigned short f2bf(float f){
  union { float f; unsigned int i; } v; v.f = f;
  unsigned int r = v.i + 0x7FFFu + ((v.i >> 16) & 1u);
  return (unsigned short)(r >> 16);
}
__device__ __forceinline__ float fast_tanh(float x){
  float e = __expf(2.f * x);
  return 1.f - 2.f / (e + 1.f);
}
__device__ __forceinline__ void gld_lds16(const void* g, void* l){
  __builtin_amdgcn_global_load_lds((const __attribute__((address_space(1))) void*)g,
                                   (__attribute__((address_space(3))) void*)l, 16, 0, 0);
}
__device__ __forceinline__ f32x4 mfma16(bf16x8 a, bf16x8 b, f32x4 c){
  return __builtin_amdgcn_mfma_f32_16x16x32_bf16(a, b, c, 0, 0, 0);
}
__device__ __forceinline__ void packA(float4 x, float4 y, unsigned short* dst){
  U16x8 pk;
  pk.s[0]=f2bf(x.x); pk.s[1]=f2bf(x.y); pk.s[2]=f2bf(x.z); pk.s[3]=f2bf(x.w);
  pk.s[4]=f2bf(y.x); pk.s[5]=f2bf(y.y); pk.s[6]=f2bf(y.z); pk.s[7]=f2bf(y.w);
  *reinterpret_cast<uint4*>(dst) = pk.u;
}

// ---------------- convert / split kernels ----------------
__device__ __forceinline__ void cat_store_a(const float* __restrict__ src,
                                            unsigned short* __restrict__ dst, int idx){
  float x = src[idx];
  int r = idx >> 9, c = idx & 511;
  unsigned short hi = f2bf(x);
  unsigned short lo = f2bf(x - bf2f(hi));
  unsigned short* p = dst + (long)r * 1536 + c;
  p[0] = hi; p[512] = lo; p[1024] = hi;
}
__device__ __forceinline__ void cat_store_w(const float* __restrict__ src,
                                            unsigned short* __restrict__ dst, int idx){
  float x = src[idx];
  int r = idx >> 9, c = idx & 511;
  unsigned short hi = f2bf(x);
  unsigned short lo = f2bf(x - bf2f(hi));
  unsigned short* p = dst + (long)r * 1536 + c;
  p[0] = hi; p[512] = hi; p[1024] = lo;
}

__global__ void k_convert(const float* W_ae, const float* W_c, const float* W_s,
                          const float* W_h, const float* W_o,
                          const float* h, const float* sent,
                          unsigned short* W_ae_bf, unsigned short* W_c_bf,
                          unsigned short* W_s_cat, unsigned short* W_h_cat,
                          unsigned short* W_o_cat, unsigned short* h_cat,
                          unsigned short* s_cat){
  int idx = blockIdx.x * 256 + threadIdx.x;
  switch (blockIdx.y) {
    case 0: if (idx < 512*2048) W_ae_bf[idx] = f2bf(W_ae[idx]); break;
    case 1: if (idx < 512*512)  W_c_bf[idx]  = f2bf(W_c[idx]);  break;
    case 2: if (idx < 512*512)  cat_store_w(W_s, W_s_cat, idx); break;
    case 3: if (idx < 512*512)  cat_store_w(W_h, W_h_cat, idx); break;
    case 4: if (idx < 512*512)  cat_store_w(W_o, W_o_cat, idx); break;
    case 5: if (idx < 1024*512) cat_store_a(h, h_cat, idx); break;
    case 6: if (idx < 1024*512) cat_store_a(sent, s_cat, idx); break;
  }
}

// ---------------- GEMM1: att = relu(att_feats @ W_ae^T + b_ae) --------------
// 128x512 tile, BK=32, TRIPLE-buffered counted-vmcnt pipeline, 8 waves (2Mx4N).
__global__ __launch_bounds__(512, 2) void k_gemm1(
    const float* __restrict__ Af, const unsigned short* __restrict__ Wb,
    const float* __restrict__ bias, unsigned short* __restrict__ Cout){
  __shared__ __align__(16) unsigned short As[3][128*32];   // 24 KB
  __shared__ __align__(16) unsigned short Bs[3][512*32];   // 96 KB
  const int tid = threadIdx.x;
  const int w = tid >> 6, l = tid & 63;
  const int wm = w >> 2, wn = w & 3;
  const long m0 = (long)blockIdx.x * 128;
  f32x4 acc[4][8];
#pragma unroll
  for (int i = 0; i < 4; ++i)
#pragma unroll
    for (int j = 0; j < 8; ++j) acc[i][j] = f32x4{0.f,0.f,0.f,0.f};

  const int arow = tid >> 2, aslot = tid & 3;
  const float* aptr = Af + (m0 + arow) * FDIM + aslot * 8;
  const int awz = arow*32 + ((aslot ^ ((arow>>1)&3)) * 8);   // verified A-write swizzle
  const int bsl = (l & 3) ^ ((l >> 3) & 3);                   // verified B-source swizzle
  const unsigned short* bptr = Wb + (long)(w*64 + (l >> 2)) * FDIM + bsl * 8;
  const int g = l >> 4, r15 = l & 15;
  const int rs = (r15 >> 1) & 3;

  const int NT = FDIM/32;  // 64
  float4 c0, c1, p0, p1;
  // ---- prologue: tiles 0 and 1 in flight ----
  c0 = *reinterpret_cast<const float4*>(aptr);          // tile0 A (2 vm)
  c1 = *reinterpret_cast<const float4*>(aptr + 4);
#pragma unroll
  for (int i = 0; i < 4; ++i)                           // tile0 B (4 vm)
    gld_lds16(bptr + (long)i*16*FDIM, &Bs[0][w*2048 + i*512]);
  p0 = *reinterpret_cast<const float4*>(aptr + 32);     // tile1 A (2 vm)
  p1 = *reinterpret_cast<const float4*>(aptr + 36);
#pragma unroll
  for (int i = 0; i < 4; ++i)                           // tile1 B (4 vm)
    gld_lds16(bptr + (long)i*16*FDIM + 32, &Bs[1][w*2048 + i*512]);
  packA(c0, c1, &As[0][awz]);                            // auto vmcnt wait for c0,c1
  c0 = p0; c1 = p1;                                      // tile1 A pending convert
  WAITV6;   // tile0 B resident (tile1's 6 ops may remain in flight)
  WAITL0; SCHED0; SBAR; SCHED0;

  int cb = 0, nb = 1, pb = 2;
  for (int kt = 0; kt < NT; ++kt) {
    if (kt + 2 < NT) {
      const float* ap2 = aptr + (kt+2)*32;
      p0 = *reinterpret_cast<const float4*>(ap2);        // A(t+2): 2 vm
      p1 = *reinterpret_cast<const float4*>(ap2 + 4);
      const long k0 = (long)(kt+2)*32;
#pragma unroll
      for (int i = 0; i < 4; ++i)                        // B(t+2): 4 vm
        gld_lds16(bptr + (long)i*16*FDIM + k0, &Bs[pb][w*2048 + i*512]);
    }
    // compute tile kt from buffer cb
    bf16x8 afr[4], bfr[8];
#pragma unroll
    for (int i = 0; i < 4; ++i)
      afr[i] = *reinterpret_cast<const bf16x8*>(&As[cb][(wm*64 + i*16 + r15)*32 + ((g^rs)*8)]);
#pragma unroll
    for (int j = 0; j < 8; ++j)
      bfr[j] = *reinterpret_cast<const bf16x8*>(&Bs[cb][(wn*128 + j*16 + r15)*32 + ((g^rs)*8)]);
    __builtin_amdgcn_s_setprio(1);
#pragma unroll
    for (int i = 0; i < 4; ++i)
#pragma unroll
      for (int j = 0; j < 8; ++j)
        acc[i][j] = mfma16(afr[i], bfr[j], acc[i][j]);
    __builtin_amdgcn_s_setprio(0);
    if (kt + 1 < NT) {
      packA(c0, c1, &As[nb][awz]);   // convert A(t+1); compiler auto-waits its vmcnt
      c0 = p0; c1 = p1;
      if (kt + 2 < NT) { WAITV6; } else { WAITV0; }   // B(t+1) resident before publish
      WAITL0; SCHED0; SBAR; SCHED0;
      int t = cb; cb = nb; nb = pb; pb = t;
    }
  }
  // ---- epilogue ----
  float bb[8];
#pragma unroll
  for (int j = 0; j < 8; ++j) bb[j] = bias[wn*128 + j*16 + r15];
#pragma unroll
  for (int i = 0; i < 4; ++i)
#pragma unroll
    for (int r = 0; r < 4; ++r) {
      long m = m0 + wm*64 + i*16 + g*4 + r;
#pragma unroll
      for (int j = 0; j < 8; ++j) {
        int n = wn*128 + j*16 + r15;
        float x = acc[i][j][r] + bb[j];
        Cout[m * RDIM + n] = f2bf(x > 0.f ? x : 0.f);
      }
    }
}

// ---- GEMM2: logits[m] = sum_n tanh(att@W_c^T + b_c + h_e[b]) * W_al[n] ----
// 128x512 tile, BK=32, triple-buffered counted-vmcnt pipeline.
__global__ __launch_bounds__(512, 2) void k_gemm2(
    const unsigned short* __restrict__ Abf, const unsigned short* __restrict__ Wb,
    const float* __restrict__ bias, const float* __restrict__ h_e,
    const float* __restrict__ W_al, float* __restrict__ logits){
  __shared__ __align__(16) unsigned short As[3][128*32];
  __shared__ __align__(16) unsigned short Bs[3][512*32];
  __shared__ float part[128][4];
  const int tid = threadIdx.x;
  const int w = tid >> 6, l = tid & 63;
  const int wm = w >> 2, wn = w & 3;
  const long m0 = (long)blockIdx.x * 128;
  f32x4 acc[4][8];
#pragma unroll
  for (int i = 0; i < 4; ++i)
#pragma unroll
    for (int j = 0; j < 8; ++j) acc[i][j] = f32x4{0.f,0.f,0.f,0.f};

  const int bsl = (l & 3) ^ ((l >> 3) & 3);
  const unsigned short* bptr = Wb + (long)(w*64 + (l >> 2)) * RDIM + bsl * 8;
  const unsigned short* aptrg = Abf + (m0 + w*16 + (l >> 2)) * RDIM + bsl * 8;
  const int g = l >> 4, r15 = l & 15;
  const int rs = (r15 >> 1) & 3;
  const int NT = RDIM/32;  // 16

  // prologue: tiles 0,1 (5 vm ops each per wave: 1 A + 4 B)
  gld_lds16(aptrg, &As[0][w*512]);
#pragma unroll
  for (int i = 0; i < 4; ++i)
    gld_lds16(bptr + (long)i*16*RDIM, &Bs[0][w*2048 + i*512]);
  gld_lds16(aptrg + 32, &As[1][w*512]);
#pragma unroll
  for (int i = 0; i < 4; ++i)
    gld_lds16(bptr + (long)i*16*RDIM + 32, &Bs[1][w*2048 + i*512]);
  WAITV5;   // tile0 resident (tile1's 5 may fly)
  SCHED0; SBAR; SCHED0;

  int cb = 0, nb = 1, pb = 2;
  for (int kt = 0; kt < NT; ++kt) {
    if (kt + 2 < NT) {
      const long k0 = (long)(kt+2)*32;
      gld_lds16(aptrg + k0, &As[pb][w*512]);
#pragma unroll
      for (int i = 0; i < 4; ++i)
        gld_lds16(bptr + (long)i*16*RDIM + k0, &Bs[pb][w*2048 + i*512]);
    }
    bf16x8 afr[4], bfr[8];
#pragma unroll
    for (int i = 0; i < 4; ++i)
      afr[i] = *reinterpret_cast<const bf16x8*>(&As[cb][(wm*64 + i*16 + r15)*32 + ((g^rs)*8)]);
#pragma unroll
    for (int j = 0; j < 8; ++j)
      bfr[j] = *reinterpret_cast<const bf16x8*>(&Bs[cb][(wn*128 + j*16 + r15)*32 + ((g^rs)*8)]);
    __builtin_amdgcn_s_setprio(1);
#pragma unroll
    for (int i = 0; i < 4; ++i)
#pragma unroll
      for (int j = 0; j < 8; ++j)
        acc[i][j] = mfma16(afr[i], bfr[j], acc[i][j]);
    __builtin_amdgcn_s_setprio(0);
    if (kt + 1 < NT) {
      if (kt + 2 < NT) { WAITV5; } else { WAITV0; }
      SCHED0; SBAR; SCHED0;
      int t = cb; cb = nb; nb = pb; pb = t;
    }
  }
  float bb[8], wa[8];
#pragma unroll
  for (int j = 0; j < 8; ++j) {
    int n = wn*128 + j*16 + r15;
    bb[j] = bias[n]; wa[j] = W_al[n];
  }
#pragma unroll
  for (int i = 0; i < 4; ++i)
#pragma unroll
    for (int r = 0; r < 4; ++r) {
      int lrow = wm*64 + i*16 + g*4 + r;
      long m = m0 + lrow;
      int b = (int)(m / SDIM);
      const float* hrow = h_e + (long)b * RDIM;
      float s = 0.f;
#pragma unroll
      for (int j = 0; j < 8; ++j) {
        int n = wn*128 + j*16 + r15;
        float x = acc[i][j][r] + bb[j] + hrow[n];
        s += fast_tanh(x) * wa[j];
      }
      s += __shfl_xor(s, 1); s += __shfl_xor(s, 2);
      s += __shfl_xor(s, 4); s += __shfl_xor(s, 8);
      if (r15 == 0) part[lrow][wn] = s;
    }
  __syncthreads();
  if (tid < 128)
    logits[m0 + tid] = part[tid][0] + part[tid][1] + part[tid][2] + part[tid][3];
}

// ---------------- small GEMM body (K=1536 hi/lo-cat), f32 out ---------------
__device__ __forceinline__ void small_gemm_body(
    const unsigned short* __restrict__ Abf, const unsigned short* __restrict__ Wb,
    const float* __restrict__ bias, float* __restrict__ Cout, int do_tanh, int bx,
    unsigned short* As, unsigned short* Bs){
  const int tid = threadIdx.x;
  const int w = tid >> 6, l = tid & 63;
  const int wm = w >> 1, wn = w & 1;
  const int m0 = (bx >> 3) * 64, n0 = (bx & 7) * 64;
  const int K = 1536;
  f32x4 acc[2][2];
#pragma unroll
  for (int i = 0; i < 2; ++i)
#pragma unroll
    for (int j = 0; j < 2; ++j) acc[i][j] = f32x4{0.f,0.f,0.f,0.f};

  const int crow = l >> 2;
  const int bsl = (l & 3) ^ ((l >> 3) & 3);

  for (int kt = 0; kt < 48; ++kt) {
    const int k0 = kt * 32;
    gld_lds16(Abf + (long)(m0 + w*16 + crow)*K + k0 + bsl*8, As + w*512);
    gld_lds16(Wb  + (long)(n0 + w*16 + crow)*K + k0 + bsl*8, Bs + w*512);
    __syncthreads();
    bf16x8 afr[2], bfr[2];
    const int g = l >> 4, r15 = l & 15;
    const int rs = (r15 >> 1) & 3;
#pragma unroll
    for (int i = 0; i < 2; ++i)
      afr[i] = *reinterpret_cast<const bf16x8*>(As + (wm*32 + i*16 + r15)*32 + ((g ^ rs)*8));
#pragma unroll
    for (int j = 0; j < 2; ++j)
      bfr[j] = *reinterpret_cast<const bf16x8*>(Bs + (wn*32 + j*16 + r15)*32 + ((g ^ rs)*8));
#pragma unroll
    for (int i = 0; i < 2; ++i)
#pragma unroll
      for (int j = 0; j < 2; ++j)
        acc[i][j] = mfma16(afr[i], bfr[j], acc[i][j]);
    __syncthreads();
  }
  const int r15 = l & 15, g = l >> 4;
#pragma unroll
  for (int i = 0; i < 2; ++i)
#pragma unroll
    for (int r = 0; r < 4; ++r) {
      int m = m0 + wm*32 + i*16 + g*4 + r;
#pragma unroll
      for (int j = 0; j < 2; ++j) {
        int n = n0 + wn*32 + j*16 + r15;
        float x = acc[i][j][r] + bias[n];
        if (do_tanh) x = fast_tanh(x);
        Cout[(long)m * 512 + n] = x;
      }
    }
}

__global__ __launch_bounds__(256) void k_gemm_small(
    const unsigned short* __restrict__ Abf, const unsigned short* __restrict__ Wb,
    const float* __restrict__ bias, float* __restrict__ Cout, int do_tanh){
  __shared__ __align__(16) unsigned short As[64*32];
  __shared__ __align__(16) unsigned short Bs[64*32];
  small_gemm_body(Abf, Wb, bias, Cout, do_tanh, blockIdx.x, As, Bs);
}

__global__ __launch_bounds__(256) void k_embed2(
    const unsigned short* __restrict__ h_cat, const unsigned short* __restrict__ W_h_cat,
    const float* __restrict__ b_h, float* __restrict__ h_e,
    const unsigned short* __restrict__ s_cat, const unsigned short* __restrict__ W_s_cat,
    const float* __restrict__ b_s, float* __restrict__ sent_e){
  __shared__ __align__(16) unsigned short As[64*32];
  __shared__ __align__(16) unsigned short Bs[64*32];
  if (blockIdx.y == 0) small_gemm_body(h_cat, W_h_cat, b_h, h_e, 0, blockIdx.x, As, Bs);
  else                 small_gemm_body(s_cat, W_s_cat, b_s, sent_e, 0, blockIdx.x, As, Bs);
}

// ------- softmax + cHat + atten_out(hi/lo cat), sentinel logit inline -------
__global__ __launch_bounds__(512) void k_softmax_chat(
    const float* __restrict__ logits, const unsigned short* __restrict__ att_bf,
    const float* __restrict__ sent, const float* __restrict__ h,
    const float* __restrict__ sent_e, const float* __restrict__ h_e,
    const float* __restrict__ W_al, unsigned short* __restrict__ atten_cat){
  __shared__ float lg[97];
  __shared__ float alpha[97];
  __shared__ float ssum_s;
  const int b = blockIdx.x;
  const int tid = threadIdx.x;
  if (tid >= 1 && tid <= 96) lg[tid] = logits[(long)b*96 + tid - 1];
  if (tid < 64) {
    float s = 0.f;
    for (int a = tid; a < 512; a += 64)
      s += fast_tanh(sent_e[(long)b*512 + a] + h_e[(long)b*512 + a]) * W_al[a];
    s += __shfl_xor(s, 1); s += __shfl_xor(s, 2); s += __shfl_xor(s, 4);
    s += __shfl_xor(s, 8); s += __shfl_xor(s, 16); s += __shfl_xor(s, 32);
    if (tid == 0) lg[0] = s;
  }
  __syncthreads();
  if (tid < 64) {
    float m = -1e30f;
    for (int i = tid; i < 97; i += 64) m = fmaxf(m, lg[i]);
#pragma unroll
    for (int k = 1; k < 64; k <<= 1) m = fmaxf(m, __shfl_xor(m, k));
    float ss = 0.f;
    for (int i = tid; i < 97; i += 64) { float e = __expf(lg[i] - m); alpha[i] = e; ss += e; }
#pragma unroll
    for (int k = 1; k < 64; k <<= 1) ss += __shfl_xor(ss, k);
    if (tid == 0) ssum_s = ss;
  }
  __syncthreads();
  if (tid < 97) alpha[tid] *= (1.f / ssum_s);
  __syncthreads();
  const int t = tid;
  float accv = alpha[0] * sent[(long)b*512 + t];
  const unsigned short* arow = att_bf + (long)b * SDIM * RDIM + t;
#pragma unroll 4
  for (int s = 0; s < SDIM; ++s)
    accv += alpha[s+1] * bf2f(arow[(long)s * RDIM]);
  float x = accv + h[(long)b*512 + t];
  unsigned short hi = f2bf(x);
  unsigned short lo = f2bf(x - bf2f(hi));
  unsigned short* p = atten_cat + (long)b*1536 + t;
  p[0] = hi; p[512] = lo; p[1024] = hi;
}

extern "C" void kernel_launch(void* const* d_in, const int* in_sizes, int n_in,
                              void* d_out, int out_size, void* d_ws, size_t ws_size,
                              hipStream_t stream){
  (void)in_sizes; (void)n_in; (void)out_size; (void)ws_size;
  const float* h    = (const float*)d_in[0];
  const float* sent = (const float*)d_in[1];
  const float* feats= (const float*)d_in[2];
  const float* W_ae = (const float*)d_in[3];
  const float* b_ae = (const float*)d_in[4];
  const float* W_c  = (const float*)d_in[5];
  const float* b_c  = (const float*)d_in[6];
  const float* W_s  = (const float*)d_in[7];
  const float* b_s  = (const float*)d_in[8];
  const float* W_h  = (const float*)d_in[9];
  const float* b_h  = (const float*)d_in[10];
  const float* W_al = (const float*)d_in[11];
  const float* W_o  = (const float*)d_in[13];
  const float* b_o  = (const float*)d_in[14];
  float* out = (float*)d_out;

  char* p = (char*)d_ws;
  unsigned short* att_bf  = (unsigned short*)p; p += (size_t)M1*512*2;
  unsigned short* W_ae_bf = (unsigned short*)p; p += (size_t)512*2048*2;
  unsigned short* W_c_bf  = (unsigned short*)p; p += (size_t)512*512*2;
  unsigned short* W_s_cat = (unsigned short*)p; p += (size_t)512*1536*2;
  unsigned short* W_h_cat = (unsigned short*)p; p += (size_t)512*1536*2;
  unsigned short* W_o_cat = (unsigned short*)p; p += (size_t)512*1536*2;
  unsigned short* h_cat   = (unsigned short*)p; p += (size_t)1024*1536*2;
  unsigned short* s_cat   = (unsigned short*)p; p += (size_t)1024*1536*2;
  unsigned short* at_cat  = (unsigned short*)p; p += (size_t)1024*1536*2;
  float* h_e    = (float*)p; p += (size_t)1024*512*4;
  float* sent_e = (float*)p; p += (size_t)1024*512*4;
  float* logits = (float*)p; p += (size_t)M1*4;

  k_convert<<<dim3(4096,7), 256, 0, stream>>>(W_ae, W_c, W_s, W_h, W_o, h, sent,
        W_ae_bf, W_c_bf, W_s_cat, W_h_cat, W_o_cat, h_cat, s_cat);
  k_embed2<<<dim3(128,2), 256, 0, stream>>>(h_cat, W_h_cat, b_h, h_e,
                                            s_cat, W_s_cat, b_s, sent_e);
  k_gemm1<<<768, 512, 0, stream>>>(feats, W_ae_bf, b_ae, att_bf);
  k_gemm2<<<768, 512, 0, stream>>>(att_bf, W_c_bf, b_c, h_e, W_al, logits);
  k_softmax_chat<<<1024, 512, 0, stream>>>(logits, att_bf, sent, h,
                                           sent_e, h_e, W_al, at_cat);
  k_gemm_small<<<128, 256, 0, stream>>>(at_cat, W_o_cat, b_o, out, 1);
}

// Round 6
// 512.493 us; speedup vs baseline: 1.0977x; 1.0977x over previous
//
#include <hip/hip_runtime.h>

#define M1 98304
#define RDIM 512
#define FDIM 2048
#define SDIM 96
#define BM 96
#define BK 64

typedef __attribute__((ext_vector_type(8))) __bf16 bf16x8;
typedef __attribute__((ext_vector_type(4))) float f32x4;

__device__ __forceinline__ float bf2f(unsigned short u){
  union { unsigned int i; float f; } v; v.i = ((unsigned int)u) << 16; return v.f;
}
__device__ __forceinline__ unsigned short f2bf(float f){
  union { float f; unsigned int i; } v; v.f = f;
  unsigned int r = v.i + 0x7FFFu + ((v.i >> 16) & 1u);
  return (unsigned short)(r >> 16);
}
__device__ __forceinline__ unsigned short f2bfn(float f){
  __bf16 b = (__bf16)f;
  return __builtin_bit_cast(unsigned short, b);
}
__device__ __forceinline__ float fast_tanh(float x){
  float e = __expf(2.f * x);
  return 1.f - 2.f / (e + 1.f);
}
__device__ __forceinline__ void gld_lds16(const void* g, void* l){
  __builtin_amdgcn_global_load_lds((const __attribute__((address_space(1))) void*)g,
                                   (__attribute__((address_space(3))) void*)l, 16, 0, 0);
}
__device__ __forceinline__ f32x4 mfma16(bf16x8 a, bf16x8 b, f32x4 c){
  return __builtin_amdgcn_mfma_f32_16x16x32_bf16(a, b, c, 0, 0, 0);
}

// ---------------- convert / split kernels (unchanged, proven) ---------------
__device__ __forceinline__ void cat_store_a(const float* __restrict__ src,
                                            unsigned short* __restrict__ dst, int idx){
  float x = src[idx];
  int r = idx >> 9, c = idx & 511;
  unsigned short hi = f2bf(x);
  unsigned short lo = f2bf(x - bf2f(hi));
  unsigned short* p = dst + (long)r * 1536 + c;
  p[0] = hi; p[512] = lo; p[1024] = hi;
}
__device__ __forceinline__ void cat_store_w(const float* __restrict__ src,
                                            unsigned short* __restrict__ dst, int idx){
  float x = src[idx];
  int r = idx >> 9, c = idx & 511;
  unsigned short hi = f2bf(x);
  unsigned short lo = f2bf(x - bf2f(hi));
  unsigned short* p = dst + (long)r * 1536 + c;
  p[0] = hi; p[512] = hi; p[1024] = lo;
}

__global__ void k_convert(const float* W_ae, const float* W_c, const float* W_s,
                          const float* W_h, const float* W_o,
                          const float* h, const float* sent,
                          unsigned short* W_ae_bf, unsigned short* W_c_bf,
                          unsigned short* W_s_cat, unsigned short* W_h_cat,
                          unsigned short* W_o_cat, unsigned short* h_cat,
                          unsigned short* s_cat){
  int idx = blockIdx.x * 256 + threadIdx.x;
  switch (blockIdx.y) {
    case 0: if (idx < 512*2048) W_ae_bf[idx] = f2bf(W_ae[idx]); break;
    case 1: if (idx < 512*512)  W_c_bf[idx]  = f2bf(W_c[idx]);  break;
    case 2: if (idx < 512*512)  cat_store_w(W_s, W_s_cat, idx); break;
    case 3: if (idx < 512*512)  cat_store_w(W_h, W_h_cat, idx); break;
    case 4: if (idx < 512*512)  cat_store_w(W_o, W_o_cat, idx); break;
    case 5: if (idx < 1024*512) cat_store_a(h, h_cat, idx); break;
    case 6: if (idx < 1024*512) cat_store_a(sent, s_cat, idx); break;
  }
}

// ---------------- GEMM1: att = relu(att_feats @ W_ae^T + b_ae) --------------
// 96x512 tile, BK=64, 2-buffer __syncthreads pipeline, 8 waves (2M x 4N).
// 48 MFMA per wave per barrier; A reg-staged w/ issue-early/convert-late (T14).
__global__ __launch_bounds__(512) void k_gemm1(
    const float* __restrict__ Af, const unsigned short* __restrict__ Wb,
    const float* __restrict__ bias, unsigned short* __restrict__ Cout){
  __shared__ __align__(16) unsigned short As[2][BM*BK];    // 24 KB
  __shared__ __align__(16) unsigned short Bs[2][512*BK];   // 128 KB
  const int tid = threadIdx.x;
  const int w = tid >> 6, l = tid & 63;
  const int wm = w >> 2, wn = w & 3;
  const long m0 = (long)blockIdx.x * BM;
  f32x4 acc[3][8];
#pragma unroll
  for (int i = 0; i < 3; ++i)
#pragma unroll
    for (int j = 0; j < 8; ++j) acc[i][j] = f32x4{0.f,0.f,0.f,0.f};

  // B staging: pre-swizzled global source, linear gld_lds dest (8 chunks/wave)
  const int brow_in = l >> 3;                       // 0..7 within 8-row chunk
  const int bswz = (l & 7) ^ brow_in;               // 16B slot
  const unsigned short* bbase = Wb + (long)(w*64 + brow_in) * FDIM + bswz*8;
  // A staging map: chunk c = tid + s*512 -> row=c>>4, kq=c&15 (float4 each)
  // fragment read indices
  const int g = l >> 4, r15 = l & 15;
  const int rs = r15 & 7;

  const int NT = FDIM / BK;  // 32

  // ---- prologue: stage tile 0 into buf 0 ----
  {
#pragma unroll
    for (int q = 0; q < 8; ++q)
      gld_lds16(bbase + (long)q*8*FDIM, &Bs[0][(w*8+q)*512]);
    float4 v[3];
#pragma unroll
    for (int s = 0; s < 3; ++s) {
      int c = tid + s*512, row = c >> 4, kq = c & 15;
      v[s] = *reinterpret_cast<const float4*>(Af + (m0+row)*FDIM + kq*4);
    }
#pragma unroll
    for (int s = 0; s < 3; ++s) {
      int c = tid + s*512, row = c >> 4, kq = c & 15;
      ushort4 pk; pk.x=f2bfn(v[s].x); pk.y=f2bfn(v[s].y); pk.z=f2bfn(v[s].z); pk.w=f2bfn(v[s].w);
      *reinterpret_cast<ushort4*>(&As[0][row*BK + ((kq ^ ((row&7)<<1))<<2)]) = pk;
    }
  }
  __syncthreads();

  int cb = 0;
  for (int kt = 0; kt < NT; ++kt) {
    const int nb = cb ^ 1;
    float4 v[3];
    const bool more = (kt + 1 < NT);
    if (more) {
      const int kof = (kt+1) * BK;
#pragma unroll
      for (int q = 0; q < 8; ++q)
        gld_lds16(bbase + (long)q*8*FDIM + kof, &Bs[nb][(w*8+q)*512]);
#pragma unroll
      for (int s = 0; s < 3; ++s) {
        int c = tid + s*512, row = c >> 4, kq = c & 15;
        v[s] = *reinterpret_cast<const float4*>(Af + (m0+row)*FDIM + kof + kq*4);
      }
    }
    // compute tile kt from buf cb
#pragma unroll
    for (int h = 0; h < 2; ++h) {
      const int ko = ((g + 4*h) ^ rs) << 3;
      bf16x8 afr[3], bfr[8];
#pragma unroll
      for (int i = 0; i < 3; ++i)
        afr[i] = *reinterpret_cast<const bf16x8*>(&As[cb][(wm*48 + i*16 + r15)*BK + ko]);
#pragma unroll
      for (int j = 0; j < 8; ++j)
        bfr[j] = *reinterpret_cast<const bf16x8*>(&Bs[cb][(wn*128 + j*16 + r15)*BK + ko]);
      __builtin_amdgcn_s_setprio(1);
#pragma unroll
      for (int i = 0; i < 3; ++i)
#pragma unroll
        for (int j = 0; j < 8; ++j)
          acc[i][j] = mfma16(afr[i], bfr[j], acc[i][j]);
      __builtin_amdgcn_s_setprio(0);
    }
    if (more) {
#pragma unroll
      for (int s = 0; s < 3; ++s) {
        int c = tid + s*512, row = c >> 4, kq = c & 15;
        ushort4 pk; pk.x=f2bfn(v[s].x); pk.y=f2bfn(v[s].y); pk.z=f2bfn(v[s].z); pk.w=f2bfn(v[s].w);
        *reinterpret_cast<ushort4*>(&As[nb][row*BK + ((kq ^ ((row&7)<<1))<<2)]) = pk;
      }
      __syncthreads();
      cb = nb;
    }
  }
  // ---- epilogue ----
  float bb[8];
#pragma unroll
  for (int j = 0; j < 8; ++j) bb[j] = bias[wn*128 + j*16 + r15];
#pragma unroll
  for (int i = 0; i < 3; ++i)
#pragma unroll
    for (int r = 0; r < 4; ++r) {
      long m = m0 + wm*48 + i*16 + g*4 + r;
#pragma unroll
      for (int j = 0; j < 8; ++j) {
        int n = wn*128 + j*16 + r15;
        float x = acc[i][j][r] + bb[j];
        Cout[m * RDIM + n] = f2bfn(x > 0.f ? x : 0.f);
      }
    }
}

// ---- GEMM2: logits[m] = sum_n tanh(att@W_c^T + b_c + h_e[b]) * W_al[n] ----
// 96x512 tile (block == one batch row-group), BK=64, same skeleton, no packA.
__global__ __launch_bounds__(512) void k_gemm2(
    const unsigned short* __restrict__ Abf, const unsigned short* __restrict__ Wb,
    const float* __restrict__ bias, const float* __restrict__ h_e,
    const float* __restrict__ W_al, float* __restrict__ logits){
  __shared__ __align__(16) unsigned short As[2][BM*BK];
  __shared__ __align__(16) unsigned short Bs[2][512*BK];
  __shared__ float part[BM][4];
  const int tid = threadIdx.x;
  const int w = tid >> 6, l = tid & 63;
  const int wm = w >> 2, wn = w & 3;
  const long m0 = (long)blockIdx.x * BM;
  f32x4 acc[3][8];
#pragma unroll
  for (int i = 0; i < 3; ++i)
#pragma unroll
    for (int j = 0; j < 8; ++j) acc[i][j] = f32x4{0.f,0.f,0.f,0.f};

  const int brow_in = l >> 3;
  const int bswz = (l & 7) ^ brow_in;
  const unsigned short* bbase = Wb + (long)(w*64 + brow_in) * RDIM + bswz*8;
  // A: 12 chunks of 8 rows; wave w -> chunk w, waves 0-3 also chunk 8+w
  const unsigned short* abase = Abf + (m0 + (long)w*8 + brow_in) * RDIM + bswz*8;
  const unsigned short* abase2 = Abf + (m0 + (long)(8+w)*8 + brow_in) * RDIM + bswz*8;
  const int g = l >> 4, r15 = l & 15;
  const int rs = r15 & 7;
  const int NT = RDIM / BK;  // 8

  {
#pragma unroll
    for (int q = 0; q < 8; ++q)
      gld_lds16(bbase + (long)q*8*RDIM, &Bs[0][(w*8+q)*512]);
    gld_lds16(abase, &As[0][w*512]);
    if (w < 4) gld_lds16(abase2, &As[0][(8+w)*512]);
  }
  __syncthreads();

  int cb = 0;
  for (int kt = 0; kt < NT; ++kt) {
    const int nb = cb ^ 1;
    const bool more = (kt + 1 < NT);
    if (more) {
      const int kof = (kt+1) * BK;
#pragma unroll
      for (int q = 0; q < 8; ++q)
        gld_lds16(bbase + (long)q*8*RDIM + kof, &Bs[nb][(w*8+q)*512]);
      gld_lds16(abase + kof, &As[nb][w*512]);
      if (w < 4) gld_lds16(abase2 + kof, &As[nb][(8+w)*512]);
    }
#pragma unroll
    for (int h = 0; h < 2; ++h) {
      const int ko = ((g + 4*h) ^ rs) << 3;
      bf16x8 afr[3], bfr[8];
#pragma unroll
      for (int i = 0; i < 3; ++i)
        afr[i] = *reinterpret_cast<const bf16x8*>(&As[cb][(wm*48 + i*16 + r15)*BK + ko]);
#pragma unroll
      for (int j = 0; j < 8; ++j)
        bfr[j] = *reinterpret_cast<const bf16x8*>(&Bs[cb][(wn*128 + j*16 + r15)*BK + ko]);
      __builtin_amdgcn_s_setprio(1);
#pragma unroll
      for (int i = 0; i < 3; ++i)
#pragma unroll
        for (int j = 0; j < 8; ++j)
          acc[i][j] = mfma16(afr[i], bfr[j], acc[i][j]);
      __builtin_amdgcn_s_setprio(0);
    }
    if (more) { __syncthreads(); cb = nb; }
  }
  // epilogue: whole block is one batch (BM==SDIM)
  const float* hrow = h_e + (long)blockIdx.x * RDIM;
  float bb[8], wa[8], he[8];
#pragma unroll
  for (int j = 0; j < 8; ++j) {
    int n = wn*128 + j*16 + r15;
    bb[j] = bias[n]; wa[j] = W_al[n]; he[j] = hrow[n];
  }
#pragma unroll
  for (int i = 0; i < 3; ++i)
#pragma unroll
    for (int r = 0; r < 4; ++r) {
      int lrow = wm*48 + i*16 + g*4 + r;
      float s = 0.f;
#pragma unroll
      for (int j = 0; j < 8; ++j) {
        float x = acc[i][j][r] + bb[j] + he[j];
        s += fast_tanh(x) * wa[j];
      }
      s += __shfl_xor(s, 1); s += __shfl_xor(s, 2);
      s += __shfl_xor(s, 4); s += __shfl_xor(s, 8);
      if (r15 == 0) part[lrow][wn] = s;
    }
  __syncthreads();
  if (tid < BM)
    logits[m0 + tid] = part[tid][0] + part[tid][1] + part[tid][2] + part[tid][3];
}

// ---------------- small GEMM body (K=1536 hi/lo-cat), f32 out ---------------
__device__ __forceinline__ void small_gemm_body(
    const unsigned short* __restrict__ Abf, const unsigned short* __restrict__ Wb,
    const float* __restrict__ bias, float* __restrict__ Cout, int do_tanh, int bx,
    unsigned short* As, unsigned short* Bs){
  const int tid = threadIdx.x;
  const int w = tid >> 6, l = tid & 63;
  const int wm = w >> 1, wn = w & 1;
  const int m0 = (bx >> 3) * 64, n0 = (bx & 7) * 64;
  const int K = 1536;
  f32x4 acc[2][2];
#pragma unroll
  for (int i = 0; i < 2; ++i)
#pragma unroll
    for (int j = 0; j < 2; ++j) acc[i][j] = f32x4{0.f,0.f,0.f,0.f};

  const int crow = l >> 2;
  const int bsl = (l & 3) ^ ((l >> 3) & 3);

  for (int kt = 0; kt < 48; ++kt) {
    const int k0 = kt * 32;
    gld_lds16(Abf + (long)(m0 + w*16 + crow)*K + k0 + bsl*8, As + w*512);
    gld_lds16(Wb  + (long)(n0 + w*16 + crow)*K + k0 + bsl*8, Bs + w*512);
    __syncthreads();
    bf16x8 afr[2], bfr[2];
    const int g = l >> 4, r15 = l & 15;
    const int rs2 = (r15 >> 1) & 3;
#pragma unroll
    for (int i = 0; i < 2; ++i)
      afr[i] = *reinterpret_cast<const bf16x8*>(As + (wm*32 + i*16 + r15)*32 + ((g ^ rs2)*8));
#pragma unroll
    for (int j = 0; j < 2; ++j)
      bfr[j] = *reinterpret_cast<const bf16x8*>(Bs + (wn*32 + j*16 + r15)*32 + ((g ^ rs2)*8));
#pragma unroll
    for (int i = 0; i < 2; ++i)
#pragma unroll
      for (int j = 0; j < 2; ++j)
        acc[i][j] = mfma16(afr[i], bfr[j], acc[i][j]);
    __syncthreads();
  }
  const int r15 = l & 15, g = l >> 4;
#pragma unroll
  for (int i = 0; i < 2; ++i)
#pragma unroll
    for (int r = 0; r < 4; ++r) {
      int m = m0 + wm*32 + i*16 + g*4 + r;
#pragma unroll
      for (int j = 0; j < 2; ++j) {
        int n = n0 + wn*32 + j*16 + r15;
        float x = acc[i][j][r] + bias[n];
        if (do_tanh) x = fast_tanh(x);
        Cout[(long)m * 512 + n] = x;
      }
    }
}

__global__ __launch_bounds__(256) void k_gemm_small(
    const unsigned short* __restrict__ Abf, const unsigned short* __restrict__ Wb,
    const float* __restrict__ bias, float* __restrict__ Cout, int do_tanh){
  __shared__ __align__(16) unsigned short As[64*32];
  __shared__ __align__(16) unsigned short Bs[64*32];
  small_gemm_body(Abf, Wb, bias, Cout, do_tanh, blockIdx.x, As, Bs);
}

__global__ __launch_bounds__(256) void k_embed2(
    const unsigned short* __restrict__ h_cat, const unsigned short* __restrict__ W_h_cat,
    const float* __restrict__ b_h, float* __restrict__ h_e,
    const unsigned short* __restrict__ s_cat, const unsigned short* __restrict__ W_s_cat,
    const float* __restrict__ b_s, float* __restrict__ sent_e){
  __shared__ __align__(16) unsigned short As[64*32];
  __shared__ __align__(16) unsigned short Bs[64*32];
  if (blockIdx.y == 0) small_gemm_body(h_cat, W_h_cat, b_h, h_e, 0, blockIdx.x, As, Bs);
  else                 small_gemm_body(s_cat, W_s_cat, b_s, sent_e, 0, blockIdx.x, As, Bs);
}

// ------- softmax + cHat + atten_out(hi/lo cat), sentinel logit inline -------
__global__ __launch_bounds__(512) void k_softmax_chat(
    const float* __restrict__ logits, const unsigned short* __restrict__ att_bf,
    const float* __restrict__ sent, const float* __restrict__ h,
    const float* __restrict__ sent_e, const float* __restrict__ h_e,
    const float* __restrict__ W_al, unsigned short* __restrict__ atten_cat){
  __shared__ float lg[97];
  __shared__ float alpha[97];
  __shared__ float ssum_s;
  const int b = blockIdx.x;
  const int tid = threadIdx.x;
  if (tid >= 1 && tid <= 96) lg[tid] = logits[(long)b*96 + tid - 1];
  if (tid < 64) {
    float s = 0.f;
    for (int a = tid; a < 512; a += 64)
      s += fast_tanh(sent_e[(long)b*512 + a] + h_e[(long)b*512 + a]) * W_al[a];
    s += __shfl_xor(s, 1); s += __shfl_xor(s, 2); s += __shfl_xor(s, 4);
    s += __shfl_xor(s, 8); s += __shfl_xor(s, 16); s += __shfl_xor(s, 32);
    if (tid == 0) lg[0] = s;
  }
  __syncthreads();
  if (tid < 64) {
    float m = -1e30f;
    for (int i = tid; i < 97; i += 64) m = fmaxf(m, lg[i]);
#pragma unroll
    for (int k = 1; k < 64; k <<= 1) m = fmaxf(m, __shfl_xor(m, k));
    float ss = 0.f;
    for (int i = tid; i < 97; i += 64) { float e = __expf(lg[i] - m); alpha[i] = e; ss += e; }
#pragma unroll
    for (int k = 1; k < 64; k <<= 1) ss += __shfl_xor(ss, k);
    if (tid == 0) ssum_s = ss;
  }
  __syncthreads();
  if (tid < 97) alpha[tid] *= (1.f / ssum_s);
  __syncthreads();
  const int t = tid;
  float accv = alpha[0] * sent[(long)b*512 + t];
  const unsigned short* arow = att_bf + (long)b * SDIM * RDIM + t;
#pragma unroll 4
  for (int s = 0; s < SDIM; ++s)
    accv += alpha[s+1] * bf2f(arow[(long)s * RDIM]);
  float x = accv + h[(long)b*512 + t];
  unsigned short hi = f2bf(x);
  unsigned short lo = f2bf(x - bf2f(hi));
  unsigned short* p = atten_cat + (long)b*1536 + t;
  p[0] = hi; p[512] = lo; p[1024] = hi;
}

extern "C" void kernel_launch(void* const* d_in, const int* in_sizes, int n_in,
                              void* d_out, int out_size, void* d_ws, size_t ws_size,
                              hipStream_t stream){
  (void)in_sizes; (void)n_in; (void)out_size; (void)ws_size;
  const float* h    = (const float*)d_in[0];
  const float* sent = (const float*)d_in[1];
  const float* feats= (const float*)d_in[2];
  const float* W_ae = (const float*)d_in[3];
  const float* b_ae = (const float*)d_in[4];
  const float* W_c  = (const float*)d_in[5];
  const float* b_c  = (const float*)d_in[6];
  const float* W_s  = (const float*)d_in[7];
  const float* b_s  = (const float*)d_in[8];
  const float* W_h  = (const float*)d_in[9];
  const float* b_h  = (const float*)d_in[10];
  const float* W_al = (const float*)d_in[11];
  const float* W_o  = (const float*)d_in[13];
  const float* b_o  = (const float*)d_in[14];
  float* out = (float*)d_out;

  char* p = (char*)d_ws;
  unsigned short* att_bf  = (unsigned short*)p; p += (size_t)M1*512*2;
  unsigned short* W_ae_bf = (unsigned short*)p; p += (size_t)512*2048*2;
  unsigned short* W_c_bf  = (unsigned short*)p; p += (size_t)512*512*2;
  unsigned short* W_s_cat = (unsigned short*)p; p += (size_t)512*1536*2;
  unsigned short* W_h_cat = (unsigned short*)p; p += (size_t)512*1536*2;
  unsigned short* W_o_cat = (unsigned short*)p; p += (size_t)512*1536*2;
  unsigned short* h_cat   = (unsigned short*)p; p += (size_t)1024*1536*2;
  unsigned short* s_cat   = (unsigned short*)p; p += (size_t)1024*1536*2;
  unsigned short* at_cat  = (unsigned short*)p; p += (size_t)1024*1536*2;
  float* h_e    = (float*)p; p += (size_t)1024*512*4;
  float* sent_e = (float*)p; p += (size_t)1024*512*4;
  float* logits = (float*)p; p += (size_t)M1*4;

  k_convert<<<dim3(4096,7), 256, 0, stream>>>(W_ae, W_c, W_s, W_h, W_o, h, sent,
        W_ae_bf, W_c_bf, W_s_cat, W_h_cat, W_o_cat, h_cat, s_cat);
  k_embed2<<<dim3(128,2), 256, 0, stream>>>(h_cat, W_h_cat, b_h, h_e,
                                            s_cat, W_s_cat, b_s, sent_e);
  k_gemm1<<<1024, 512, 0, stream>>>(feats, W_ae_bf, b_ae, att_bf);
  k_gemm2<<<1024, 512, 0, stream>>>(att_bf, W_c_bf, b_c, h_e, W_al, logits);
  k_softmax_chat<<<1024, 512, 0, stream>>>(logits, att_bf, sent, h,
                                           sent_e, h_e, W_al, at_cat);
  k_gemm_small<<<128, 256, 0, stream>>>(at_cat, W_o_cat, b_o, out, 1);
}

// Round 7
// 450.196 us; speedup vs baseline: 1.2496x; 1.1384x over previous
//
#include <hip/hip_runtime.h>

#define M1 98304
#define RDIM 512
#define FDIM 2048
#define SDIM 96
#define BM 96
#define BK 64

typedef __attribute__((ext_vector_type(8))) __bf16 bf16x8;
typedef __attribute__((ext_vector_type(4))) float f32x4;

__device__ __forceinline__ float bf2f(unsigned short u){
  union { unsigned int i; float f; } v; v.i = ((unsigned int)u) << 16; return v.f;
}
__device__ __forceinline__ unsigned short f2bf(float f){
  union { float f; unsigned int i; } v; v.f = f;
  unsigned int r = v.i + 0x7FFFu + ((v.i >> 16) & 1u);
  return (unsigned short)(r >> 16);
}
__device__ __forceinline__ unsigned short f2bfn(float f){
  __bf16 b = (__bf16)f;
  return __builtin_bit_cast(unsigned short, b);
}
__device__ __forceinline__ float fast_tanh(float x){
  float e = __expf(2.f * x);
  return 1.f - 2.f / (e + 1.f);
}
__device__ __forceinline__ void gld_lds16(const void* g, void* l){
  __builtin_amdgcn_global_load_lds((const __attribute__((address_space(1))) void*)g,
                                   (__attribute__((address_space(3))) void*)l, 16, 0, 0);
}
__device__ __forceinline__ f32x4 mfma16(bf16x8 a, bf16x8 b, f32x4 c){
  return __builtin_amdgcn_mfma_f32_16x16x32_bf16(a, b, c, 0, 0, 0);
}

// ---------------- convert / split kernels (unchanged, proven) ---------------
__device__ __forceinline__ void cat_store_a(const float* __restrict__ src,
                                            unsigned short* __restrict__ dst, int idx){
  float x = src[idx];
  int r = idx >> 9, c = idx & 511;
  unsigned short hi = f2bf(x);
  unsigned short lo = f2bf(x - bf2f(hi));
  unsigned short* p = dst + (long)r * 1536 + c;
  p[0] = hi; p[512] = lo; p[1024] = hi;
}
__device__ __forceinline__ void cat_store_w(const float* __restrict__ src,
                                            unsigned short* __restrict__ dst, int idx){
  float x = src[idx];
  int r = idx >> 9, c = idx & 511;
  unsigned short hi = f2bf(x);
  unsigned short lo = f2bf(x - bf2f(hi));
  unsigned short* p = dst + (long)r * 1536 + c;
  p[0] = hi; p[512] = hi; p[1024] = lo;
}

__global__ void k_convert(const float* W_ae, const float* W_c, const float* W_s,
                          const float* W_h, const float* W_o,
                          const float* h, const float* sent,
                          unsigned short* W_ae_bf, unsigned short* W_c_bf,
                          unsigned short* W_s_cat, unsigned short* W_h_cat,
                          unsigned short* W_o_cat, unsigned short* h_cat,
                          unsigned short* s_cat){
  int idx = blockIdx.x * 256 + threadIdx.x;
  switch (blockIdx.y) {
    case 0: if (idx < 512*2048) W_ae_bf[idx] = f2bf(W_ae[idx]); break;
    case 1: if (idx < 512*512)  W_c_bf[idx]  = f2bf(W_c[idx]);  break;
    case 2: if (idx < 512*512)  cat_store_w(W_s, W_s_cat, idx); break;
    case 3: if (idx < 512*512)  cat_store_w(W_h, W_h_cat, idx); break;
    case 4: if (idx < 512*512)  cat_store_w(W_o, W_o_cat, idx); break;
    case 5: if (idx < 1024*512) cat_store_a(h, h_cat, idx); break;
    case 6: if (idx < 1024*512) cat_store_a(sent, s_cat, idx); break;
  }
}

// =================== FUSED: gemm1 + gemm2 + softmax + cHat ==================
// One block = one batch. Phase1: att=relu(feats@Wae^T+b) -> LDS (bf16, swz).
// Phase2: logits = alpha_net(tanh(att@Wc^T + b_c + h_e)). Then softmax, cHat,
// atten_out hi/lo-cat store. att never touches HBM.
__global__ __launch_bounds__(512) void k_fused(
    const float* __restrict__ Af, const unsigned short* __restrict__ Wae,
    const float* __restrict__ b_ae,
    const unsigned short* __restrict__ Wcg, const float* __restrict__ b_c,
    const float* __restrict__ h_e, const float* __restrict__ W_al,
    const float* __restrict__ sent_e, const float* __restrict__ sent,
    const float* __restrict__ hvec, unsigned short* __restrict__ atten_cat){
  __shared__ __align__(16) char smem[155648];            // 152 KB (R6 precedent)
  unsigned short* As   = (unsigned short*)smem;          // ph1 [2][96*64]   24576 B
  unsigned short* Bs   = (unsigned short*)(smem + 24576);// ph1 [2][512*64] 131072 B
  unsigned short* attL = (unsigned short*)smem;          // ph2 [96*512]     98304 B
  unsigned short* Wcs  = (unsigned short*)(smem + 98304);// ph2 [512*32]     32768 B
  float* part = (float*)(smem + 131072);                 // [96][4]
  float* lg   = (float*)(smem + 131072 + 1536);          // [97]
  float* alp  = (float*)(smem + 131072 + 1536 + 512);    // [97]
  float* ssum = (float*)(smem + 131072 + 1536 + 1024);

  const int tid = threadIdx.x;
  const int w = tid >> 6, l = tid & 63;
  const int wm = w >> 2, wn = w & 3;
  const int b = blockIdx.x;
  const long m0 = (long)b * BM;
  const int g = l >> 4, r15 = l & 15;
  const int rs = r15 & 7;

  f32x4 acc[3][8];
#pragma unroll
  for (int i = 0; i < 3; ++i)
#pragma unroll
    for (int j = 0; j < 8; ++j) acc[i][j] = f32x4{0.f,0.f,0.f,0.f};

  // ---------------- phase 1 (R6 gemm1 loop, verbatim geometry) --------------
  {
    const int brow_in = l >> 3;
    const int bswz = (l & 7) ^ brow_in;
    const unsigned short* bbase = Wae + (long)(w*64 + brow_in) * FDIM + bswz*8;
    const int NT = FDIM / BK;  // 32

    {  // prologue: tile 0 -> buf 0
#pragma unroll
      for (int q = 0; q < 8; ++q)
        gld_lds16(bbase + (long)q*8*FDIM, Bs + (w*8+q)*512);
      float4 v[3];
#pragma unroll
      for (int s = 0; s < 3; ++s) {
        int c = tid + s*512, row = c >> 4, kq = c & 15;
        v[s] = *reinterpret_cast<const float4*>(Af + (m0+row)*FDIM + kq*4);
      }
#pragma unroll
      for (int s = 0; s < 3; ++s) {
        int c = tid + s*512, row = c >> 4, kq = c & 15;
        ushort4 pk; pk.x=f2bfn(v[s].x); pk.y=f2bfn(v[s].y); pk.z=f2bfn(v[s].z); pk.w=f2bfn(v[s].w);
        *reinterpret_cast<ushort4*>(&As[row*BK + ((kq ^ ((row&7)<<1))<<2)]) = pk;
      }
    }
    __syncthreads();

    int cb = 0;
    for (int kt = 0; kt < NT; ++kt) {
      const int nb = cb ^ 1;
      float4 v[3];
      const bool more = (kt + 1 < NT);
      if (more) {
        const int kof = (kt+1) * BK;
#pragma unroll
        for (int q = 0; q < 8; ++q)
          gld_lds16(bbase + (long)q*8*FDIM + kof, Bs + nb*32768 + (w*8+q)*512);
#pragma unroll
        for (int s = 0; s < 3; ++s) {
          int c = tid + s*512, row = c >> 4, kq = c & 15;
          v[s] = *reinterpret_cast<const float4*>(Af + (m0+row)*FDIM + kof + kq*4);
        }
      }
#pragma unroll
      for (int hh = 0; hh < 2; ++hh) {
        const int ko = ((g + 4*hh) ^ rs) << 3;
        bf16x8 afr[3], bfr[8];
#pragma unroll
        for (int i = 0; i < 3; ++i)
          afr[i] = *reinterpret_cast<const bf16x8*>(&As[cb*6144 + (wm*48 + i*16 + r15)*BK + ko]);
#pragma unroll
        for (int j = 0; j < 8; ++j)
          bfr[j] = *reinterpret_cast<const bf16x8*>(&Bs[cb*32768 + (wn*128 + j*16 + r15)*BK + ko]);
        __builtin_amdgcn_s_setprio(1);
#pragma unroll
        for (int i = 0; i < 3; ++i)
#pragma unroll
          for (int j = 0; j < 8; ++j)
            acc[i][j] = mfma16(afr[i], bfr[j], acc[i][j]);
        __builtin_amdgcn_s_setprio(0);
      }
      if (more) {
#pragma unroll
        for (int s = 0; s < 3; ++s) {
          int c = tid + s*512, row = c >> 4, kq = c & 15;
          ushort4 pk; pk.x=f2bfn(v[s].x); pk.y=f2bfn(v[s].y); pk.z=f2bfn(v[s].z); pk.w=f2bfn(v[s].w);
          *reinterpret_cast<ushort4*>(&As[nb*6144 + row*BK + ((kq ^ ((row&7)<<1))<<2)]) = pk;
        }
        __syncthreads();
        cb = nb;
      }
    }
  }
  // phase-1 epilogue: relu(acc+bias) -> attL (bf16, grp^(row&7) swizzle)
  __syncthreads();
  {
    float bb[8];
#pragma unroll
    for (int j = 0; j < 8; ++j) bb[j] = b_ae[wn*128 + j*16 + r15];
#pragma unroll
    for (int i = 0; i < 3; ++i)
#pragma unroll
      for (int r = 0; r < 4; ++r) {
        int row = wm*48 + i*16 + g*4 + r;
        int rs8 = row & 7;
#pragma unroll
        for (int j = 0; j < 8; ++j) {
          int col = wn*128 + j*16 + r15;
          float x = acc[i][j][r] + bb[j];
          x = x > 0.f ? x : 0.f;
          attL[row*512 + (((col>>3) ^ rs8)<<3) + (col&7)] = f2bfn(x);
        }
      }
  }
  __syncthreads();

  // ---------------- phase 2: att @ Wc^T (A from attL, B single-buf BK=32) ---
#pragma unroll
  for (int i = 0; i < 3; ++i)
#pragma unroll
    for (int j = 0; j < 8; ++j) acc[i][j] = f32x4{0.f,0.f,0.f,0.f};
  {
    const int crow = l >> 2;
    const int bsl2 = (l & 3) ^ ((l >> 3) & 3);
    const int rs2 = (r15 >> 1) & 3;
    for (int kt = 0; kt < 16; ++kt) {
#pragma unroll
      for (int i = 0; i < 4; ++i)
        gld_lds16(Wcg + (long)(w*64 + i*16 + crow)*RDIM + kt*32 + bsl2*8,
                  Wcs + w*2048 + i*512);
      __syncthreads();
      bf16x8 afr[3], bfr[8];
#pragma unroll
      for (int i = 0; i < 3; ++i) {
        int ra = wm*48 + i*16 + r15;
        int grp = (kt<<2) + g;
        afr[i] = *reinterpret_cast<const bf16x8*>(&attL[ra*512 + ((grp ^ rs)<<3)]);
      }
#pragma unroll
      for (int j = 0; j < 8; ++j)
        bfr[j] = *reinterpret_cast<const bf16x8*>(&Wcs[(wn*128 + j*16 + r15)*32 + ((g ^ rs2)<<3)]);
      __builtin_amdgcn_s_setprio(1);
#pragma unroll
      for (int i = 0; i < 3; ++i)
#pragma unroll
        for (int j = 0; j < 8; ++j)
          acc[i][j] = mfma16(afr[i], bfr[j], acc[i][j]);
      __builtin_amdgcn_s_setprio(0);
      __syncthreads();
    }
  }
  // logits epilogue (verbatim R6 gemm2 math)
  {
    const float* hrow = h_e + (long)b * RDIM;
    float bb2[8], wa[8], he[8];
#pragma unroll
    for (int j = 0; j < 8; ++j) {
      int n = wn*128 + j*16 + r15;
      bb2[j] = b_c[n]; wa[j] = W_al[n]; he[j] = hrow[n];
    }
#pragma unroll
    for (int i = 0; i < 3; ++i)
#pragma unroll
      for (int r = 0; r < 4; ++r) {
        int lrow = wm*48 + i*16 + g*4 + r;
        float s = 0.f;
#pragma unroll
        for (int j = 0; j < 8; ++j) {
          float x = acc[i][j][r] + bb2[j] + he[j];
          s += fast_tanh(x) * wa[j];
        }
        s += __shfl_xor(s, 1); s += __shfl_xor(s, 2);
        s += __shfl_xor(s, 4); s += __shfl_xor(s, 8);
        if (r15 == 0) part[lrow*4 + wn] = s;
      }
  }
  __syncthreads();
  if (tid < 96)
    lg[1+tid] = part[tid*4+0] + part[tid*4+1] + part[tid*4+2] + part[tid*4+3];
  if (tid < 64) {   // sentinel logit
    float s = 0.f;
    for (int a = tid; a < 512; a += 64)
      s += fast_tanh(sent_e[(long)b*512 + a] + h_e[(long)b*512 + a]) * W_al[a];
    s += __shfl_xor(s, 1); s += __shfl_xor(s, 2); s += __shfl_xor(s, 4);
    s += __shfl_xor(s, 8); s += __shfl_xor(s, 16); s += __shfl_xor(s, 32);
    if (tid == 0) lg[0] = s;
  }
  __syncthreads();
  if (tid < 64) {   // softmax over 97
    float m = -1e30f;
    for (int i = tid; i < 97; i += 64) m = fmaxf(m, lg[i]);
#pragma unroll
    for (int k = 1; k < 64; k <<= 1) m = fmaxf(m, __shfl_xor(m, k));
    float ss = 0.f;
    for (int i = tid; i < 97; i += 64) { float e = __expf(lg[i] - m); alp[i] = e; ss += e; }
#pragma unroll
    for (int k = 1; k < 64; k <<= 1) ss += __shfl_xor(ss, k);
    if (tid == 0) ssum[0] = ss;
  }
  __syncthreads();
  if (tid < 97) alp[tid] *= (1.f / ssum[0]);
  __syncthreads();
  // cHat + atten_out (hi/lo cat)
  {
    const int col = tid;
    const int cg = col >> 3, ch = col & 7;
    float accv = alp[0] * sent[(long)b*512 + col];
#pragma unroll 4
    for (int s = 0; s < SDIM; ++s)
      accv += alp[s+1] * bf2f(attL[s*512 + ((cg ^ (s&7))<<3) + ch]);
    float x = accv + hvec[(long)b*512 + col];
    unsigned short hi = f2bf(x);
    unsigned short lo = f2bf(x - bf2f(hi));
    unsigned short* pp = atten_cat + (long)b*1536 + col;
    pp[0] = hi; pp[512] = lo; pp[1024] = hi;
  }
}

// ---------------- small GEMM body (K=1536 hi/lo-cat), f32 out ---------------
__device__ __forceinline__ void small_gemm_body(
    const unsigned short* __restrict__ Abf, const unsigned short* __restrict__ Wb,
    const float* __restrict__ bias, float* __restrict__ Cout, int do_tanh, int bx,
    unsigned short* As, unsigned short* Bs){
  const int tid = threadIdx.x;
  const int w = tid >> 6, l = tid & 63;
  const int wm = w >> 1, wn = w & 1;
  const int m0 = (bx >> 3) * 64, n0 = (bx & 7) * 64;
  const int K = 1536;
  f32x4 acc[2][2];
#pragma unroll
  for (int i = 0; i < 2; ++i)
#pragma unroll
    for (int j = 0; j < 2; ++j) acc[i][j] = f32x4{0.f,0.f,0.f,0.f};

  const int crow = l >> 2;
  const int bsl = (l & 3) ^ ((l >> 3) & 3);

  for (int kt = 0; kt < 48; ++kt) {
    const int k0 = kt * 32;
    gld_lds16(Abf + (long)(m0 + w*16 + crow)*K + k0 + bsl*8, As + w*512);
    gld_lds16(Wb  + (long)(n0 + w*16 + crow)*K + k0 + bsl*8, Bs + w*512);
    __syncthreads();
    bf16x8 afr[2], bfr[2];
    const int g = l >> 4, r15 = l & 15;
    const int rs2 = (r15 >> 1) & 3;
#pragma unroll
    for (int i = 0; i < 2; ++i)
      afr[i] = *reinterpret_cast<const bf16x8*>(As + (wm*32 + i*16 + r15)*32 + ((g ^ rs2)*8));
#pragma unroll
    for (int j = 0; j < 2; ++j)
      bfr[j] = *reinterpret_cast<const bf16x8*>(Bs + (wn*32 + j*16 + r15)*32 + ((g ^ rs2)*8));
#pragma unroll
    for (int i = 0; i < 2; ++i)
#pragma unroll
      for (int j = 0; j < 2; ++j)
        acc[i][j] = mfma16(afr[i], bfr[j], acc[i][j]);
    __syncthreads();
  }
  const int r15 = l & 15, g = l >> 4;
#pragma unroll
  for (int i = 0; i < 2; ++i)
#pragma unroll
    for (int r = 0; r < 4; ++r) {
      int m = m0 + wm*32 + i*16 + g*4 + r;
#pragma unroll
      for (int j = 0; j < 2; ++j) {
        int n = n0 + wn*32 + j*16 + r15;
        float x = acc[i][j][r] + bias[n];
        if (do_tanh) x = fast_tanh(x);
        Cout[(long)m * 512 + n] = x;
      }
    }
}

__global__ __launch_bounds__(256) void k_gemm_small(
    const unsigned short* __restrict__ Abf, const unsigned short* __restrict__ Wb,
    const float* __restrict__ bias, float* __restrict__ Cout, int do_tanh){
  __shared__ __align__(16) unsigned short As[64*32];
  __shared__ __align__(16) unsigned short Bs[64*32];
  small_gemm_body(Abf, Wb, bias, Cout, do_tanh, blockIdx.x, As, Bs);
}

__global__ __launch_bounds__(256) void k_embed2(
    const unsigned short* __restrict__ h_cat, const unsigned short* __restrict__ W_h_cat,
    const float* __restrict__ b_h, float* __restrict__ h_e,
    const unsigned short* __restrict__ s_cat, const unsigned short* __restrict__ W_s_cat,
    const float* __restrict__ b_s, float* __restrict__ sent_e){
  __shared__ __align__(16) unsigned short As[64*32];
  __shared__ __align__(16) unsigned short Bs[64*32];
  if (blockIdx.y == 0) small_gemm_body(h_cat, W_h_cat, b_h, h_e, 0, blockIdx.x, As, Bs);
  else                 small_gemm_body(s_cat, W_s_cat, b_s, sent_e, 0, blockIdx.x, As, Bs);
}

extern "C" void kernel_launch(void* const* d_in, const int* in_sizes, int n_in,
                              void* d_out, int out_size, void* d_ws, size_t ws_size,
                              hipStream_t stream){
  (void)in_sizes; (void)n_in; (void)out_size; (void)ws_size;
  const float* h    = (const float*)d_in[0];
  const float* sent = (const float*)d_in[1];
  const float* feats= (const float*)d_in[2];
  const float* W_ae = (const float*)d_in[3];
  const float* b_ae = (const float*)d_in[4];
  const float* W_c  = (const float*)d_in[5];
  const float* b_c  = (const float*)d_in[6];
  const float* W_s  = (const float*)d_in[7];
  const float* b_s  = (const float*)d_in[8];
  const float* W_h  = (const float*)d_in[9];
  const float* b_h  = (const float*)d_in[10];
  const float* W_al = (const float*)d_in[11];
  const float* W_o  = (const float*)d_in[13];
  const float* b_o  = (const float*)d_in[14];
  float* out = (float*)d_out;

  char* p = (char*)d_ws;
  unsigned short* W_ae_bf = (unsigned short*)p; p += (size_t)512*2048*2;
  unsigned short* W_c_bf  = (unsigned short*)p; p += (size_t)512*512*2;
  unsigned short* W_s_cat = (unsigned short*)p; p += (size_t)512*1536*2;
  unsigned short* W_h_cat = (unsigned short*)p; p += (size_t)512*1536*2;
  unsigned short* W_o_cat = (unsigned short*)p; p += (size_t)512*1536*2;
  unsigned short* h_cat   = (unsigned short*)p; p += (size_t)1024*1536*2;
  unsigned short* s_cat   = (unsigned short*)p; p += (size_t)1024*1536*2;
  unsigned short* at_cat  = (unsigned short*)p; p += (size_t)1024*1536*2;
  float* h_e    = (float*)p; p += (size_t)1024*512*4;
  float* sent_e = (float*)p; p += (size_t)1024*512*4;

  k_convert<<<dim3(4096,7), 256, 0, stream>>>(W_ae, W_c, W_s, W_h, W_o, h, sent,
        W_ae_bf, W_c_bf, W_s_cat, W_h_cat, W_o_cat, h_cat, s_cat);
  k_embed2<<<dim3(128,2), 256, 0, stream>>>(h_cat, W_h_cat, b_h, h_e,
                                            s_cat, W_s_cat, b_s, sent_e);
  k_fused<<<1024, 512, 0, stream>>>(feats, W_ae_bf, b_ae, W_c_bf, b_c,
                                    h_e, W_al, sent_e, sent, h, at_cat);
  k_gemm_small<<<128, 256, 0, stream>>>(at_cat, W_o_cat, b_o, out, 1);
}

// Round 8
// 416.475 us; speedup vs baseline: 1.3507x; 1.0810x over previous
//
#include <hip/hip_runtime.h>

#define M1 98304
#define RDIM 512
#define FDIM 2048
#define SDIM 96
#define BM 96
#define BK 64

typedef __attribute__((ext_vector_type(8))) __bf16 bf16x8;
typedef __attribute__((ext_vector_type(4))) float f32x4;

#define WAITV6 asm volatile("s_waitcnt vmcnt(6)" ::: "memory")
#define WAITV3 asm volatile("s_waitcnt vmcnt(3)" ::: "memory")
#define WAITV0 asm volatile("s_waitcnt vmcnt(0)" ::: "memory")
#define WAITL0 asm volatile("s_waitcnt lgkmcnt(0)" ::: "memory")
#define SBAR   __builtin_amdgcn_s_barrier()
#define SCHED0 __builtin_amdgcn_sched_barrier(0)

__device__ __forceinline__ float bf2f(unsigned short u){
  union { unsigned int i; float f; } v; v.i = ((unsigned int)u) << 16; return v.f;
}
__device__ __forceinline__ unsigned short f2bf(float f){
  union { float f; unsigned int i; } v; v.f = f;
  unsigned int r = v.i + 0x7FFFu + ((v.i >> 16) & 1u);
  return (unsigned short)(r >> 16);
}
__device__ __forceinline__ unsigned short f2bfn(float f){
  __bf16 b = (__bf16)f;
  return __builtin_bit_cast(unsigned short, b);
}
__device__ __forceinline__ float fast_tanh(float x){
  float e = __expf(2.f * x);
  return 1.f - 2.f / (e + 1.f);
}
__device__ __forceinline__ void gld_lds16(const void* g, void* l){
  __builtin_amdgcn_global_load_lds((const __attribute__((address_space(1))) void*)g,
                                   (__attribute__((address_space(3))) void*)l, 16, 0, 0);
}
__device__ __forceinline__ f32x4 mfma16(bf16x8 a, bf16x8 b, f32x4 c){
  return __builtin_amdgcn_mfma_f32_16x16x32_bf16(a, b, c, 0, 0, 0);
}

// ---------------- convert / split kernels ----------------
__device__ __forceinline__ void cat_store_a(const float* __restrict__ src,
                                            unsigned short* __restrict__ dst, int idx){
  float x = src[idx];
  int r = idx >> 9, c = idx & 511;
  unsigned short hi = f2bf(x);
  unsigned short lo = f2bf(x - bf2f(hi));
  unsigned short* p = dst + (long)r * 1536 + c;
  p[0] = hi; p[512] = lo; p[1024] = hi;
}
__device__ __forceinline__ void cat_store_w(const float* __restrict__ src,
                                            unsigned short* __restrict__ dst, int idx){
  float x = src[idx];
  int r = idx >> 9, c = idx & 511;
  unsigned short hi = f2bf(x);
  unsigned short lo = f2bf(x - bf2f(hi));
  unsigned short* p = dst + (long)r * 1536 + c;
  p[0] = hi; p[512] = hi; p[1024] = lo;
}

__global__ void k_convert(const float* W_ae, const float* W_c, const float* W_s,
                          const float* W_h, const float* W_o,
                          const float* h, const float* sent,
                          unsigned short* W_ae_bf, unsigned short* W_c_bf,
                          unsigned short* W_s_cat, unsigned short* W_h_cat,
                          unsigned short* W_o_cat, unsigned short* h_cat,
                          unsigned short* s_cat){
  const int stride = 1024 * 256;
  int i0 = blockIdx.x * 256 + threadIdx.x;
  switch (blockIdx.y) {
    case 0: for (int i = i0; i < 512*2048; i += stride) W_ae_bf[i] = f2bf(W_ae[i]); break;
    case 1: for (int i = i0; i < 512*512;  i += stride) W_c_bf[i]  = f2bf(W_c[i]);  break;
    case 2: for (int i = i0; i < 512*512;  i += stride) cat_store_w(W_s, W_s_cat, i); break;
    case 3: for (int i = i0; i < 512*512;  i += stride) cat_store_w(W_h, W_h_cat, i); break;
    case 4: for (int i = i0; i < 512*512;  i += stride) cat_store_w(W_o, W_o_cat, i); break;
    case 5: for (int i = i0; i < 1024*512; i += stride) cat_store_a(h, h_cat, i); break;
    case 6: for (int i = i0; i < 1024*512; i += stride) cat_store_a(sent, s_cat, i); break;
  }
}

// =================== FUSED: gemm1 + gemm2 + softmax + cHat ==================
__global__ __launch_bounds__(512) void k_fused(
    const float* __restrict__ Af, const unsigned short* __restrict__ Wae,
    const float* __restrict__ b_ae,
    const unsigned short* __restrict__ Wcg, const float* __restrict__ b_c,
    const float* __restrict__ h_e, const float* __restrict__ W_al,
    const float* __restrict__ sent_e, const float* __restrict__ sent,
    const float* __restrict__ hvec, unsigned short* __restrict__ atten_cat){
  __shared__ __align__(16) char smem[155648];
  unsigned short* As   = (unsigned short*)smem;          // ph1 [2][96*64]
  unsigned short* Bs   = (unsigned short*)(smem + 24576);// ph1 [2][512*64]
  unsigned short* attL = (unsigned short*)smem;          // ph2 [96*512]
  unsigned short* Wcs  = (unsigned short*)(smem + 98304);// ph2 [512*32]
  float* part = (float*)(smem + 131072);
  float* lg   = (float*)(smem + 131072 + 1536);
  float* alp  = (float*)(smem + 131072 + 1536 + 512);
  float* ssum = (float*)(smem + 131072 + 1536 + 1024);

  const int tid = threadIdx.x;
  const int w = tid >> 6, l = tid & 63;
  const int wm = w >> 2, wn = w & 3;
  const int b = blockIdx.x;
  const long m0 = (long)b * BM;
  const int g = l >> 4, r15 = l & 15;
  const int rs = r15 & 7;

  f32x4 acc[3][8];
#pragma unroll
  for (int i = 0; i < 3; ++i)
#pragma unroll
    for (int j = 0; j < 8; ++j) acc[i][j] = f32x4{0.f,0.f,0.f,0.f};

  // ---------------- phase 1: counted-vmcnt pipeline ------------------------
  {
    const int brow_in = l >> 3;
    const int bswz = (l & 7) ^ brow_in;
    const unsigned short* bbase = Wae + (long)(w*64 + brow_in) * FDIM + bswz*8;
    // A chunk map: c = tid + s*512 -> row=c>>4, kq=c&15
    int arow[3], akq[3], aswz[3];
    const float* abase[3];
#pragma unroll
    for (int s = 0; s < 3; ++s) {
      int c = tid + s*512;
      arow[s] = c >> 4; akq[s] = c & 15;
      abase[s] = Af + (m0 + arow[s])*FDIM + akq[s]*4;
      aswz[s] = arow[s]*BK + ((akq[s] ^ ((arow[s]&7)<<1))<<2);
    }
    const int NT = FDIM / BK;  // 32
    float4 d0,d1,d2, e0,e1,e2;
    float4 f0 = {0,0,0,0}, f1 = {0,0,0,0}, f2 = {0,0,0,0};

    // prologue: A(0)c, B(0), A(1)d, A(2)e ; pack c; waitv6; barrier
    {
      float4 c0 = *reinterpret_cast<const float4*>(abase[0]);
      float4 c1 = *reinterpret_cast<const float4*>(abase[1]);
      float4 c2 = *reinterpret_cast<const float4*>(abase[2]);
      SCHED0;
#pragma unroll
      for (int q = 0; q < 8; ++q)
        gld_lds16(bbase + (long)q*8*FDIM, Bs + (w*8+q)*512);
      SCHED0;
      d0 = *reinterpret_cast<const float4*>(abase[0] + BK);
      d1 = *reinterpret_cast<const float4*>(abase[1] + BK);
      d2 = *reinterpret_cast<const float4*>(abase[2] + BK);
      e0 = *reinterpret_cast<const float4*>(abase[0] + 2*BK);
      e1 = *reinterpret_cast<const float4*>(abase[1] + 2*BK);
      e2 = *reinterpret_cast<const float4*>(abase[2] + 2*BK);
      SCHED0;
      ushort4 p0; p0.x=f2bfn(c0.x); p0.y=f2bfn(c0.y); p0.z=f2bfn(c0.z); p0.w=f2bfn(c0.w);
      ushort4 p1; p1.x=f2bfn(c1.x); p1.y=f2bfn(c1.y); p1.z=f2bfn(c1.z); p1.w=f2bfn(c1.w);
      ushort4 p2; p2.x=f2bfn(c2.x); p2.y=f2bfn(c2.y); p2.z=f2bfn(c2.z); p2.w=f2bfn(c2.w);
      *reinterpret_cast<ushort4*>(&As[aswz[0]]) = p0;
      *reinterpret_cast<ushort4*>(&As[aswz[1]]) = p1;
      *reinterpret_cast<ushort4*>(&As[aswz[2]]) = p2;
      WAITV6; WAITL0; SCHED0; SBAR; SCHED0;
    }

    int cb = 0;
    for (int kt = 0; kt < NT; ++kt) {
      const int nb = cb ^ 1;
      if (kt + 1 < NT) {
        const int kof = (kt+1) * BK;
#pragma unroll
        for (int q = 0; q < 8; ++q)
          gld_lds16(bbase + (long)q*8*FDIM + kof, Bs + nb*32768 + (w*8+q)*512);
      }
      SCHED0;
      if (kt + 3 < NT) {
        const int kof = (kt+3) * BK;
        f0 = *reinterpret_cast<const float4*>(abase[0] + kof);
        f1 = *reinterpret_cast<const float4*>(abase[1] + kof);
        f2 = *reinterpret_cast<const float4*>(abase[2] + kof);
      }
      SCHED0;
#pragma unroll
      for (int hh = 0; hh < 2; ++hh) {
        const int ko = ((g + 4*hh) ^ rs) << 3;
        bf16x8 afr[3], bfr[8];
#pragma unroll
        for (int i = 0; i < 3; ++i)
          afr[i] = *reinterpret_cast<const bf16x8*>(&As[cb*6144 + (wm*48 + i*16 + r15)*BK + ko]);
#pragma unroll
        for (int j = 0; j < 8; ++j)
          bfr[j] = *reinterpret_cast<const bf16x8*>(&Bs[cb*32768 + (wn*128 + j*16 + r15)*BK + ko]);
        __builtin_amdgcn_s_setprio(1);
#pragma unroll
        for (int i = 0; i < 3; ++i)
#pragma unroll
          for (int j = 0; j < 8; ++j)
            acc[i][j] = mfma16(afr[i], bfr[j], acc[i][j]);
        __builtin_amdgcn_s_setprio(0);
      }
      if (kt + 1 < NT) {
        ushort4 p0; p0.x=f2bfn(d0.x); p0.y=f2bfn(d0.y); p0.z=f2bfn(d0.z); p0.w=f2bfn(d0.w);
        ushort4 p1; p1.x=f2bfn(d1.x); p1.y=f2bfn(d1.y); p1.z=f2bfn(d1.z); p1.w=f2bfn(d1.w);
        ushort4 p2; p2.x=f2bfn(d2.x); p2.y=f2bfn(d2.y); p2.z=f2bfn(d2.z); p2.w=f2bfn(d2.w);
        *reinterpret_cast<ushort4*>(&As[nb*6144 + aswz[0]]) = p0;
        *reinterpret_cast<ushort4*>(&As[nb*6144 + aswz[1]]) = p1;
        *reinterpret_cast<ushort4*>(&As[nb*6144 + aswz[2]]) = p2;
        d0=e0; d1=e1; d2=e2; e0=f0; e1=f1; e2=f2;
        if (kt + 3 < NT) { WAITV3; } else { WAITV0; }
        WAITL0; SCHED0; SBAR; SCHED0;
        cb = nb;
      }
    }
  }
  __syncthreads();
  // phase-1 epilogue: relu(acc+bias) -> attL (bf16, grp^(row&7) swizzle)
  {
    float bb[8];
#pragma unroll
    for (int j = 0; j < 8; ++j) bb[j] = b_ae[wn*128 + j*16 + r15];
#pragma unroll
    for (int i = 0; i < 3; ++i)
#pragma unroll
      for (int r = 0; r < 4; ++r) {
        int row = wm*48 + i*16 + g*4 + r;
        int rs8 = row & 7;
#pragma unroll
        for (int j = 0; j < 8; ++j) {
          int col = wn*128 + j*16 + r15;
          float x = acc[i][j][r] + bb[j];
          x = x > 0.f ? x : 0.f;
          attL[row*512 + (((col>>3) ^ rs8)<<3) + (col&7)] = f2bfn(x);
        }
      }
  }
  __syncthreads();

  // ------- phase 2: att @ Wc^T, W_c reg-staged (T14), lgkm-only barriers ----
#pragma unroll
  for (int i = 0; i < 3; ++i)
#pragma unroll
    for (int j = 0; j < 8; ++j) acc[i][j] = f32x4{0.f,0.f,0.f,0.f};
  {
    const int crow = l >> 2;
    const int bsl2 = (l & 3) ^ ((l >> 3) & 3);
    const int rs2 = (r15 >> 1) & 3;
    uint4 rr0, rr1, rr2, rr3;
    rr0 = *reinterpret_cast<const uint4*>(Wcg + (long)(w*64 + 0*16 + crow)*RDIM + bsl2*8);
    rr1 = *reinterpret_cast<const uint4*>(Wcg + (long)(w*64 + 1*16 + crow)*RDIM + bsl2*8);
    rr2 = *reinterpret_cast<const uint4*>(Wcg + (long)(w*64 + 2*16 + crow)*RDIM + bsl2*8);
    rr3 = *reinterpret_cast<const uint4*>(Wcg + (long)(w*64 + 3*16 + crow)*RDIM + bsl2*8);
    for (int kt = 0; kt < 16; ++kt) {
      *reinterpret_cast<uint4*>(&Wcs[w*2048 + 0*512 + l*8]) = rr0;
      *reinterpret_cast<uint4*>(&Wcs[w*2048 + 1*512 + l*8]) = rr1;
      *reinterpret_cast<uint4*>(&Wcs[w*2048 + 2*512 + l*8]) = rr2;
      *reinterpret_cast<uint4*>(&Wcs[w*2048 + 3*512 + l*8]) = rr3;
      if (kt < 15) {
        const int k0 = (kt+1)*32;
        rr0 = *reinterpret_cast<const uint4*>(Wcg + (long)(w*64 + 0*16 + crow)*RDIM + k0 + bsl2*8);
        rr1 = *reinterpret_cast<const uint4*>(Wcg + (long)(w*64 + 1*16 + crow)*RDIM + k0 + bsl2*8);
        rr2 = *reinterpret_cast<const uint4*>(Wcg + (long)(w*64 + 2*16 + crow)*RDIM + k0 + bsl2*8);
        rr3 = *reinterpret_cast<const uint4*>(Wcg + (long)(w*64 + 3*16 + crow)*RDIM + k0 + bsl2*8);
      }
      WAITL0; SCHED0; SBAR; SCHED0;
      bf16x8 afr[3], bfr[8];
#pragma unroll
      for (int i = 0; i < 3; ++i) {
        int ra = wm*48 + i*16 + r15;
        int grp = (kt<<2) + g;
        afr[i] = *reinterpret_cast<const bf16x8*>(&attL[ra*512 + ((grp ^ rs)<<3)]);
      }
#pragma unroll
      for (int j = 0; j < 8; ++j)
        bfr[j] = *reinterpret_cast<const bf16x8*>(&Wcs[(wn*128 + j*16 + r15)*32 + ((g ^ rs2)<<3)]);
      __builtin_amdgcn_s_setprio(1);
#pragma unroll
      for (int i = 0; i < 3; ++i)
#pragma unroll
        for (int j = 0; j < 8; ++j)
          acc[i][j] = mfma16(afr[i], bfr[j], acc[i][j]);
      __builtin_amdgcn_s_setprio(0);
      WAITL0; SCHED0; SBAR; SCHED0;
    }
  }
  // logits epilogue
  {
    const float* hrow = h_e + (long)b * RDIM;
    float bb2[8], wa[8], he[8];
#pragma unroll
    for (int j = 0; j < 8; ++j) {
      int n = wn*128 + j*16 + r15;
      bb2[j] = b_c[n]; wa[j] = W_al[n]; he[j] = hrow[n];
    }
#pragma unroll
    for (int i = 0; i < 3; ++i)
#pragma unroll
      for (int r = 0; r < 4; ++r) {
        int lrow = wm*48 + i*16 + g*4 + r;
        float s = 0.f;
#pragma unroll
        for (int j = 0; j < 8; ++j) {
          float x = acc[i][j][r] + bb2[j] + he[j];
          s += fast_tanh(x) * wa[j];
        }
        s += __shfl_xor(s, 1); s += __shfl_xor(s, 2);
        s += __shfl_xor(s, 4); s += __shfl_xor(s, 8);
        if (r15 == 0) part[lrow*4 + wn] = s;
      }
  }
  __syncthreads();
  if (tid < 96)
    lg[1+tid] = part[tid*4+0] + part[tid*4+1] + part[tid*4+2] + part[tid*4+3];
  if (tid < 64) {
    float s = 0.f;
    for (int a = tid; a < 512; a += 64)
      s += fast_tanh(sent_e[(long)b*512 + a] + h_e[(long)b*512 + a]) * W_al[a];
    s += __shfl_xor(s, 1); s += __shfl_xor(s, 2); s += __shfl_xor(s, 4);
    s += __shfl_xor(s, 8); s += __shfl_xor(s, 16); s += __shfl_xor(s, 32);
    if (tid == 0) lg[0] = s;
  }
  __syncthreads();
  if (tid < 64) {
    float m = -1e30f;
    for (int i = tid; i < 97; i += 64) m = fmaxf(m, lg[i]);
#pragma unroll
    for (int k = 1; k < 64; k <<= 1) m = fmaxf(m, __shfl_xor(m, k));
    float ss = 0.f;
    for (int i = tid; i < 97; i += 64) { float e = __expf(lg[i] - m); alp[i] = e; ss += e; }
#pragma unroll
    for (int k = 1; k < 64; k <<= 1) ss += __shfl_xor(ss, k);
    if (tid == 0) ssum[0] = ss;
  }
  __syncthreads();
  if (tid < 97) alp[tid] *= (1.f / ssum[0]);
  __syncthreads();
  {
    const int col = tid;
    const int cg = col >> 3, ch = col & 7;
    float accv = alp[0] * sent[(long)b*512 + col];
#pragma unroll 4
    for (int s = 0; s < SDIM; ++s)
      accv += alp[s+1] * bf2f(attL[s*512 + ((cg ^ (s&7))<<3) + ch]);
    float x = accv + hvec[(long)b*512 + col];
    unsigned short hi = f2bf(x);
    unsigned short lo = f2bf(x - bf2f(hi));
    unsigned short* pp = atten_cat + (long)b*1536 + col;
    pp[0] = hi; pp[512] = lo; pp[1024] = hi;
  }
}

// ---------------- small GEMM body (K=1536 hi/lo-cat), dbuf ------------------
__device__ __forceinline__ void small_gemm_body(
    const unsigned short* __restrict__ Abf, const unsigned short* __restrict__ Wb,
    const float* __restrict__ bias, float* __restrict__ Cout, int do_tanh, int bx,
    unsigned short* As, unsigned short* Bs){
  const int tid = threadIdx.x;
  const int w = tid >> 6, l = tid & 63;
  const int wm = w >> 1, wn = w & 1;
  const int m0 = (bx >> 3) * 64, n0 = (bx & 7) * 64;
  const int K = 1536;
  f32x4 acc[2][2];
#pragma unroll
  for (int i = 0; i < 2; ++i)
#pragma unroll
    for (int j = 0; j < 2; ++j) acc[i][j] = f32x4{0.f,0.f,0.f,0.f};

  const int crow = l >> 2;
  const int bsl = (l & 3) ^ ((l >> 3) & 3);
  const unsigned short* arow_p = Abf + (long)(m0 + w*16 + crow)*K + bsl*8;
  const unsigned short* brow_p = Wb  + (long)(n0 + w*16 + crow)*K + bsl*8;

  gld_lds16(arow_p, As + w*512);
  gld_lds16(brow_p, Bs + w*512);
  __syncthreads();
  int cb = 0;
  for (int kt = 0; kt < 48; ++kt) {
    const int nb = cb ^ 1;
    if (kt + 1 < 48) {
      const int k0 = (kt+1) * 32;
      gld_lds16(arow_p + k0, As + nb*2048 + w*512);
      gld_lds16(brow_p + k0, Bs + nb*2048 + w*512);
    }
    bf16x8 afr[2], bfr[2];
    const int g = l >> 4, r15 = l & 15;
    const int rs2 = (r15 >> 1) & 3;
#pragma unroll
    for (int i = 0; i < 2; ++i)
      afr[i] = *reinterpret_cast<const bf16x8*>(As + cb*2048 + (wm*32 + i*16 + r15)*32 + ((g ^ rs2)*8));
#pragma unroll
    for (int j = 0; j < 2; ++j)
      bfr[j] = *reinterpret_cast<const bf16x8*>(Bs + cb*2048 + (wn*32 + j*16 + r15)*32 + ((g ^ rs2)*8));
#pragma unroll
    for (int i = 0; i < 2; ++i)
#pragma unroll
      for (int j = 0; j < 2; ++j)
        acc[i][j] = mfma16(afr[i], bfr[j], acc[i][j]);
    if (kt + 1 < 48) { __syncthreads(); cb = nb; }
  }
  const int r15 = l & 15, g = l >> 4;
#pragma unroll
  for (int i = 0; i < 2; ++i)
#pragma unroll
    for (int r = 0; r < 4; ++r) {
      int m = m0 + wm*32 + i*16 + g*4 + r;
#pragma unroll
      for (int j = 0; j < 2; ++j) {
        int n = n0 + wn*32 + j*16 + r15;
        float x = acc[i][j][r] + bias[n];
        if (do_tanh) x = fast_tanh(x);
        Cout[(long)m * 512 + n] = x;
      }
    }
}

__global__ __launch_bounds__(256) void k_gemm_small(
    const unsigned short* __restrict__ Abf, const unsigned short* __restrict__ Wb,
    const float* __restrict__ bias, float* __restrict__ Cout, int do_tanh){
  __shared__ __align__(16) unsigned short As[2*64*32];
  __shared__ __align__(16) unsigned short Bs[2*64*32];
  small_gemm_body(Abf, Wb, bias, Cout, do_tanh, blockIdx.x, As, Bs);
}

__global__ __launch_bounds__(256) void k_embed2(
    const unsigned short* __restrict__ h_cat, const unsigned short* __restrict__ W_h_cat,
    const float* __restrict__ b_h, float* __restrict__ h_e,
    const unsigned short* __restrict__ s_cat, const unsigned short* __restrict__ W_s_cat,
    const float* __restrict__ b_s, float* __restrict__ sent_e){
  __shared__ __align__(16) unsigned short As[2*64*32];
  __shared__ __align__(16) unsigned short Bs[2*64*32];
  if (blockIdx.y == 0) small_gemm_body(h_cat, W_h_cat, b_h, h_e, 0, blockIdx.x, As, Bs);
  else                 small_gemm_body(s_cat, W_s_cat, b_s, sent_e, 0, blockIdx.x, As, Bs);
}

extern "C" void kernel_launch(void* const* d_in, const int* in_sizes, int n_in,
                              void* d_out, int out_size, void* d_ws, size_t ws_size,
                              hipStream_t stream){
  (void)in_sizes; (void)n_in; (void)out_size; (void)ws_size;
  const float* h    = (const float*)d_in[0];
  const float* sent = (const float*)d_in[1];
  const float* feats= (const float*)d_in[2];
  const float* W_ae = (const float*)d_in[3];
  const float* b_ae = (const float*)d_in[4];
  const float* W_c  = (const float*)d_in[5];
  const float* b_c  = (const float*)d_in[6];
  const float* W_s  = (const float*)d_in[7];
  const float* b_s  = (const float*)d_in[8];
  const float* W_h  = (const float*)d_in[9];
  const float* b_h  = (const float*)d_in[10];
  const float* W_al = (const float*)d_in[11];
  const float* W_o  = (const float*)d_in[13];
  const float* b_o  = (const float*)d_in[14];
  float* out = (float*)d_out;

  char* p = (char*)d_ws;
  unsigned short* W_ae_bf = (unsigned short*)p; p += (size_t)512*2048*2;
  unsigned short* W_c_bf  = (unsigned short*)p; p += (size_t)512*512*2;
  unsigned short* W_s_cat = (unsigned short*)p; p += (size_t)512*1536*2;
  unsigned short* W_h_cat = (unsigned short*)p; p += (size_t)512*1536*2;
  unsigned short* W_o_cat = (unsigned short*)p; p += (size_t)512*1536*2;
  unsigned short* h_cat   = (unsigned short*)p; p += (size_t)1024*1536*2;
  unsigned short* s_cat   = (unsigned short*)p; p += (size_t)1024*1536*2;
  unsigned short* at_cat  = (unsigned short*)p; p += (size_t)1024*1536*2;
  float* h_e    = (float*)p; p += (size_t)1024*512*4;
  float* sent_e = (float*)p; p += (size_t)1024*512*4;

  k_convert<<<dim3(1024,7), 256, 0, stream>>>(W_ae, W_c, W_s, W_h, W_o, h, sent,
        W_ae_bf, W_c_bf, W_s_cat, W_h_cat, W_o_cat, h_cat, s_cat);
  k_embed2<<<dim3(128,2), 256, 0, stream>>>(h_cat, W_h_cat, b_h, h_e,
                                            s_cat, W_s_cat, b_s, sent_e);
  k_fused<<<1024, 512, 0, stream>>>(feats, W_ae_bf, b_ae, W_c_bf, b_c,
                                    h_e, W_al, sent_e, sent, h, at_cat);
  k_gemm_small<<<128, 256, 0, stream>>>(at_cat, W_o_cat, b_o, out, 1);
}